// Round 2
// baseline (280.873 us; speedup 1.0000x reference)
//
#include <hip/hip_runtime.h>
#include <math.h>

#define THREADS 256

// Exact JAX threefry2x32 (20 rounds, key schedule every 4), key = (0, 42).
__device__ __forceinline__ void tf2x32(unsigned x0, unsigned x1,
                                       unsigned &o0, unsigned &o1) {
  const unsigned k0 = 0u;
  const unsigned k1 = 42u;
  const unsigned k2 = 0x1BD11BDAu ^ k0 ^ k1;
  x0 += k0; x1 += k1;
#define TF_R(r) { x0 += x1; x1 = (x1 << (r)) | (x1 >> (32 - (r))); x1 ^= x0; }
  TF_R(13) TF_R(15) TF_R(26) TF_R(6)
  x0 += k1; x1 += k2 + 1u;
  TF_R(17) TF_R(29) TF_R(16) TF_R(24)
  x0 += k2; x1 += k0 + 2u;
  TF_R(13) TF_R(15) TF_R(26) TF_R(6)
  x0 += k0; x1 += k1 + 3u;
  TF_R(17) TF_R(29) TF_R(16) TF_R(24)
  x0 += k1; x1 += k2 + 4u;
  TF_R(13) TF_R(15) TF_R(26) TF_R(6)
  x0 += k2; x1 += k0 + 5u;
#undef TF_R
  o0 = x0; o1 = x1;
}

__global__ __launch_bounds__(THREADS, 2)
void wtf_reinforce_kernel(const float* __restrict__ events,
                          const float* __restrict__ W1, const float* __restrict__ b1,
                          const float* __restrict__ g1, const float* __restrict__ be1,
                          const float* __restrict__ W2, const float* __restrict__ b2,
                          const float* __restrict__ g2, const float* __restrict__ be2,
                          const float* __restrict__ W3, const float* __restrict__ b3,
                          const float* __restrict__ g3, const float* __restrict__ be3,
                          const float* __restrict__ W4, const float* __restrict__ b4,
                          const float* __restrict__ W5, const float* __restrict__ b5,
                          float* __restrict__ out_chosen,
                          float* __restrict__ out_logp,
                          int B) {
  // All weights converted to double in LDS once per block (~35.5 KB).
  __shared__ double sW1[32 * 50]; __shared__ double sb1[50];
  __shared__ double ss1[50];      __shared__ double sbe1[50];
  __shared__ double sW2[50 * 30]; __shared__ double sb2[30];
  __shared__ double ss2[30];      __shared__ double sbe2[30];
  __shared__ double sW3[30 * 20]; __shared__ double sb3[20];
  __shared__ double ss3[20];      __shared__ double sbe3[20];
  __shared__ double sW4[20 * 15]; __shared__ double sb4[15];
  __shared__ double sW5[15 * 8];  __shared__ double sb5[8];

  const int t = threadIdx.x;
  const double denom = sqrt(1.0 + 1e-5);  // BN eval: g / sqrt(1 + eps)

  for (int i = t; i < 1600; i += THREADS) sW1[i] = (double)W1[i];
  for (int i = t; i < 1500; i += THREADS) sW2[i] = (double)W2[i];
  for (int i = t; i < 600;  i += THREADS) sW3[i] = (double)W3[i];
  for (int i = t; i < 300;  i += THREADS) sW4[i] = (double)W4[i];
  for (int i = t; i < 120;  i += THREADS) sW5[i] = (double)W5[i];
  if (t < 50) { sb1[t] = (double)b1[t]; ss1[t] = (double)g1[t] / denom; sbe1[t] = (double)be1[t]; }
  if (t < 30) { sb2[t] = (double)b2[t]; ss2[t] = (double)g2[t] / denom; sbe2[t] = (double)be2[t]; }
  if (t < 20) { sb3[t] = (double)b3[t]; ss3[t] = (double)g3[t] / denom; sbe3[t] = (double)be3[t]; }
  if (t < 15) { sb4[t] = (double)b4[t]; }
  if (t < 8)  { sb5[t] = (double)b5[t]; }
  __syncthreads();

  const int b = blockIdx.x * THREADS + t;
  if (b >= B) return;

  // ---- load one row of events (32 floats, float4-vectorized) ----
  double x[32];
  const float4* ev4 = reinterpret_cast<const float4*>(events) + (size_t)b * 8;
#pragma unroll
  for (int q = 0; q < 8; ++q) {
    float4 v = ev4[q];
    x[4 * q + 0] = (double)v.x;
    x[4 * q + 1] = (double)v.y;
    x[4 * q + 2] = (double)v.z;
    x[4 * q + 3] = (double)v.w;
  }

  // ---- layer 1: 32 -> 50, BN(eval) + ReLU ----
  double a1[50];
#pragma unroll
  for (int n = 0; n < 50; ++n) {
    double acc = 0.0;
#pragma unroll
    for (int k = 0; k < 32; ++k) acc = fma(x[k], sW1[k * 50 + n], acc);
    acc += sb1[n];
    acc = acc * ss1[n] + sbe1[n];
    a1[n] = acc > 0.0 ? acc : 0.0;
  }

  // ---- layer 2: 50 -> 30, BN(eval) + ReLU ----
  double a2[30];
#pragma unroll
  for (int n = 0; n < 30; ++n) {
    double acc = 0.0;
#pragma unroll
    for (int k = 0; k < 50; ++k) acc = fma(a1[k], sW2[k * 30 + n], acc);
    acc += sb2[n];
    acc = acc * ss2[n] + sbe2[n];
    a2[n] = acc > 0.0 ? acc : 0.0;
  }

  // ---- layer 3: 30 -> 20, BN(eval) + ReLU ----
  double a3[20];
#pragma unroll
  for (int n = 0; n < 20; ++n) {
    double acc = 0.0;
#pragma unroll
    for (int k = 0; k < 30; ++k) acc = fma(a2[k], sW3[k * 20 + n], acc);
    acc += sb3[n];
    acc = acc * ss3[n] + sbe3[n];
    a3[n] = acc > 0.0 ? acc : 0.0;
  }

  // ---- layer 4: 20 -> 15, ReLU (no BN) ----
  double a4[15];
#pragma unroll
  for (int n = 0; n < 15; ++n) {
    double acc = 0.0;
#pragma unroll
    for (int k = 0; k < 20; ++k) acc = fma(a3[k], sW4[k * 15 + n], acc);
    acc += sb4[n];
    a4[n] = acc > 0.0 ? acc : 0.0;
  }

  // ---- layer 5: 15 -> 8, sigmoid ----
  double p[8];
#pragma unroll
  for (int n = 0; n < 8; ++n) {
    double acc = 0.0;
#pragma unroll
    for (int k = 0; k < 15; ++k) acc = fma(a4[k], sW5[k * 8 + n], acc);
    acc += sb5[n];
    p[n] = 1.0 / (1.0 + exp(-acc));
  }

  // ---- exact JAX bernoulli(key=42, 1-p) + log-prob ----
  // PARTITIONABLE threefry (jax_threefry_partitionable=True, modern default):
  // per-element 64-bit flat counter j: (hi, lo) = (j >> 32, j & 0xffffffff);
  // (o0, o1) = threefry2x32(key, hi, lo); 32-bit bits = o0 ^ o1.
  // Here N = 8*B < 2^32 so hi = 0.
  double prod = 1.0;
  float ch[8];
#pragma unroll
  for (int w = 0; w < 8; ++w) {
    unsigned j = 8u * (unsigned)b + (unsigned)w;
    unsigned o0, o1;
    tf2x32(0u, j, o0, o1);
    unsigned bits = o0 ^ o1;
    float u = __uint_as_float(0x3F800000u | (bits >> 9)) - 1.0f;  // [0,1), exact
    double thr = 1.0 - p[w];
    bool choice = ((double)u < thr);          // bernoulli(1-p) == 1
    ch[w] = choice ? 0.0f : 1.0f;             // chosen_events_np = 1 - choice
    prod *= choice ? thr : p[w];              // |choice - p|
  }

  float4* oc = reinterpret_cast<float4*>(out_chosen) + (size_t)b * 2;
  oc[0] = make_float4(ch[0], ch[1], ch[2], ch[3]);
  oc[1] = make_float4(ch[4], ch[5], ch[6], ch[7]);
  out_logp[b] = (float)log(prod);
}

extern "C" void kernel_launch(void* const* d_in, const int* in_sizes, int n_in,
                              void* d_out, int out_size, void* d_ws, size_t ws_size,
                              hipStream_t stream) {
  const float* events = (const float*)d_in[0];
  const float* W1  = (const float*)d_in[1];
  const float* b1  = (const float*)d_in[2];
  const float* g1  = (const float*)d_in[3];
  const float* be1 = (const float*)d_in[4];
  const float* W2  = (const float*)d_in[5];
  const float* b2  = (const float*)d_in[6];
  const float* g2  = (const float*)d_in[7];
  const float* be2 = (const float*)d_in[8];
  const float* W3  = (const float*)d_in[9];
  const float* b3  = (const float*)d_in[10];
  const float* g3  = (const float*)d_in[11];
  const float* be3 = (const float*)d_in[12];
  const float* W4  = (const float*)d_in[13];
  const float* b4  = (const float*)d_in[14];
  const float* W5  = (const float*)d_in[15];
  const float* b5  = (const float*)d_in[16];

  const int B = in_sizes[0] / 32;  // 524288
  float* out = (float*)d_out;
  float* out_chosen = out;                      // (B, 8)
  float* out_logp   = out + (size_t)B * 8;      // (B,)

  const int blocks = (B + THREADS - 1) / THREADS;
  hipLaunchKernelGGL(wtf_reinforce_kernel, dim3(blocks), dim3(THREADS), 0, stream,
                     events, W1, b1, g1, be1, W2, b2, g2, be2,
                     W3, b3, g3, be3, W4, b4, W5, b5,
                     out_chosen, out_logp, B);
}